// Round 17
// baseline (101.042 us; speedup 1.0000x reference)
//
#include <hip/hip_runtime.h>
#include <hip/hip_bf16.h>

#define DIM 768
#define NTOK 32768
#define TTOK 16
#define NBLK 128
#define GRID_MAIN 1280

typedef __attribute__((ext_vector_type(8))) short short8;
typedef __attribute__((ext_vector_type(4))) float f32x4;

__device__ __forceinline__ unsigned short f2bf(float f) {
  union { float f; unsigned int u; } v; v.f = f;
  unsigned int u = v.u;
  return (unsigned short)((u + 0x7fffu + ((u >> 16) & 1u)) >> 16);
}
__device__ __forceinline__ float bf2f(unsigned short u) {
  union { unsigned int u; float f; } v; v.u = ((unsigned int)u) << 16; return v.f;
}

// ---- pass 1: per-(block,expert) histogram
__global__ void hist_kernel(const int* __restrict__ mask, int* __restrict__ hist) {
  int tid = threadIdx.x, b = blockIdx.x;
  int gid = b * 256 + tid;
  int wv = tid >> 6, lane = tid & 63;
  int e = mask[gid] & 3;
  __shared__ int wcnt[4][4];
  #pragma unroll
  for (int q = 0; q < 4; ++q) {
    unsigned long long m = __ballot(e == q);
    if (lane == 0) wcnt[wv][q] = __popcll(m);
  }
  __syncthreads();
  if (tid < 4)
    hist[tid * NBLK + b] = wcnt[0][tid] + wcnt[1][tid] + wcnt[2][tid] + wcnt[3][tid];
}

// ---- pass 2: single-wave exclusive scan over 512 (expert-major) entries
__global__ void scan_kernel(const int* __restrict__ hist, int* __restrict__ base,
                            int* __restrict__ meta) {
  int lane = threadIdx.x;  // 64 threads
  int v[8];
  int lsum = 0;
  #pragma unroll
  for (int j = 0; j < 8; ++j) {
    int t = hist[lane * 8 + j];
    v[j] = lsum; lsum += t;
  }
  int inc = lsum;
  #pragma unroll
  for (int d = 1; d < 64; d <<= 1) {
    int u = __shfl_up(inc, d);
    if (lane >= d) inc += u;
  }
  int excl = inc - lsum;
  #pragma unroll
  for (int j = 0; j < 8; ++j) base[lane * 8 + j] = excl + v[j];
  __syncthreads();
  if (lane == 0) {
    int est[5];
    #pragma unroll
    for (int e = 0; e < 4; ++e) est[e] = base[e * NBLK];
    est[4] = NTOK;
    int s = 0;
    #pragma unroll
    for (int e = 0; e < 5; ++e) meta[e] = est[e];
    #pragma unroll
    for (int e = 0; e < 4; ++e) {
      meta[8 + e] = s;
      s += (est[e + 1] - est[e] + TTOK - 1) / TTOK;
    }
    meta[12] = s;
  }
}

// ---- pass 3: scatter tokens to exact sorted positions
__global__ void scatter_kernel(const int* __restrict__ mask, const int* __restrict__ base,
                               int* __restrict__ lists) {
  int tid = threadIdx.x, b = blockIdx.x;
  int gid = b * 256 + tid;
  int wv = tid >> 6, lane = tid & 63;
  int e = mask[gid] & 3;
  __shared__ int wcnt[4][4];
  __shared__ int wbase[4][4];
  unsigned long long lt = (1ull << lane) - 1ull;
  int rank = 0;
  #pragma unroll
  for (int q = 0; q < 4; ++q) {
    unsigned long long m = __ballot(e == q);
    if (e == q) rank = __popcll(m & lt);
    if (lane == 0) wcnt[wv][q] = __popcll(m);
  }
  __syncthreads();
  if (tid < 4) {
    int s = 0;
    #pragma unroll
    for (int w2 = 0; w2 < 4; ++w2) { int c = wcnt[w2][tid]; wbase[w2][tid] = s; s += c; }
  }
  __syncthreads();
  lists[base[e * NBLK + b] + wbase[wv][e] + rank] = gid;
}

// ---- weight repack to bf16 (WdT [ds][768], WuT [768][KP] zero-padded)
__global__ void prep_kernel(const float* __restrict__ Wd0, const float* __restrict__ Wd1,
                            const float* __restrict__ Wd2, const float* __restrict__ Wd3,
                            const float* __restrict__ Wu0, const float* __restrict__ Wu1,
                            const float* __restrict__ Wu2, const float* __restrict__ Wu3,
                            unsigned short* __restrict__ wdT, unsigned short* __restrict__ wuT) {
  int e = blockIdx.x;
  int ds = 16 << e;
  int lgK = (e == 0) ? 5 : (4 + e);
  int KP = 1 << lgK;
  const float* Wd = (e == 0) ? Wd0 : (e == 1) ? Wd1 : (e == 2) ? Wd2 : Wd3;
  const float* Wu = (e == 0) ? Wu0 : (e == 1) ? Wu1 : (e == 2) ? Wu2 : Wu3;
  const int WOFF[4] = {0, 12288, 36864, 86016};
  const int UOFF[4] = {0, 24576, 49152, 98304};
  int stride = gridDim.y * 256;
  int start = blockIdx.y * 256 + threadIdx.x;
  int nd = ds * DIM;
  for (int i = start; i < nd; i += stride) {
    int k = i / DIM, d = i - k * DIM;
    wdT[WOFF[e] + i] = f2bf(Wd[d * ds + k]);
  }
  int nu = DIM << lgK;
  for (int i = start; i < nu; i += stride) {
    int dc = i >> lgK, k = i & (KP - 1);
    wuT[UOFF[e] + i] = (k < ds) ? f2bf(Wu[k * DIM + dc]) : (unsigned short)0;
  }
}

// Prefetched state for the NEXT tile: all 4 token ids of this wave's quad,
// plus the x-data of rows 0-1 (rows 2-3 are loaded at convert time).
struct Pref {
  float4 v[6];
  int tk[4];
};

__device__ __forceinline__ void issue_prefetch(
    int w, int wv, int lane,
    const int* __restrict__ meta, const int* __restrict__ lists,
    const float* __restrict__ x, Pref& p) {
  const int* ts = meta + 8;
  int e = (w >= ts[2]) ? ((w >= ts[3]) ? 3 : 2) : ((w >= ts[1]) ? 1 : 0);
  int base = (w - ts[e]) * TTOK;
  int cnt = meta[e + 1] - meta[e];
  const int* listsE = lists + meta[e];
  #pragma unroll
  for (int i = 0; i < 4; ++i) {
    int r = base + wv * 4 + i;
    p.tk[i] = (r < cnt) ? listsE[r] : -1;
  }
  #pragma unroll
  for (int i = 0; i < 2; ++i) {
    int t = p.tk[i];
    const float* src = x + (size_t)((t >= 0) ? t : 0) * DIM;
    #pragma unroll
    for (int j = 0; j < 3; ++j) {
      float4 vv = {0.f, 0.f, 0.f, 0.f};
      if (t >= 0) vv = *(const float4*)(src + j * 256 + lane * 4);
      p.v[i * 3 + j] = vv;
    }
  }
}

// ---- per-tile compute: phases A/B (depth-1 weight rotation) + burst stage-out
template <int E>
__device__ __forceinline__ void moe_tile(
    int wv, int lane, int tid,
    const float* __restrict__ x,
    const unsigned short* __restrict__ wdT, const unsigned short* __restrict__ wuT,
    const float* __restrict__ bd, const float* __restrict__ bu,
    float* __restrict__ out, const int mytk[4],
    unsigned short* xsol, float* dnpart, unsigned short (*dn)[136]) {
  constexpr int DS = 16 << E;
  constexpr int KP = (E == 0) ? 32 : DS;
  constexpr int NTA = DS / 16;
  constexpr int SPLIT_N = (NTA < 4) ? NTA : 4;   // 1,2,4,4
  constexpr int SPLIT_K = 4 / SPLIT_N;           // 4,2,1,1
  constexpr int NTB = NTA / SPLIT_N;             // 1,1,1,2
  constexpr int KLEN = DIM / SPLIT_K;            // 192,384,768,768
  constexpr int KB = KP / 32;                    // 1,1,2,4
  constexpr int NIT = KLEN / 64;                 // 3,6,12,12
  constexpr int WOFF[4] = {0, 12288, 36864, 86016};
  constexpr int UOFF[4] = {0, 24576, 49152, 98304};
  const unsigned short* wd = wdT + WOFF[E];
  const unsigned short* wu = wuT + UOFF[E];
  #define XS(r) (xsol + (r) * 776)
  #define OL(r) (xsol + (r) * 772)

  int lrow = lane & 15, kg = lane >> 4;

  if (SPLIT_K > 1) {
    for (int i = tid; i < TTOK * DS; i += 256) dnpart[i] = 0.f;
  }
  __syncthreads();   // xs staged by all waves + dnpart zeroed

  // ---- phase A: dn = relu(X @ Wd + bd); B-fragments rotated 1 iter ahead
  int nsub = wv % SPLIT_N, ksub = wv / SPLIT_N;
  int d_base = ksub * KLEN;
  const unsigned short* xrow = XS(lrow) + d_base + kg * 8;
  const unsigned short* wr[NTB];
  #pragma unroll
  for (int nb = 0; nb < NTB; ++nb)
    wr[nb] = wd + (size_t)((nsub * NTB + nb) * 16 + lrow) * DIM + d_base + kg * 8;

  f32x4 acc[NTB];
  #pragma unroll
  for (int nb = 0; nb < NTB; ++nb) acc[nb] = f32x4{0.f, 0.f, 0.f, 0.f};

  short8 bc0[NTB], bc1[NTB];
  #pragma unroll
  for (int nb = 0; nb < NTB; ++nb) {
    bc0[nb] = *(const short8*)(wr[nb]);
    bc1[nb] = *(const short8*)(wr[nb] + 32);
  }
  #pragma unroll 2
  for (int it = 0; it < NIT; ++it) {
    short8 bn0[NTB], bn1[NTB];
    if (it + 1 < NIT) {
      #pragma unroll
      for (int nb = 0; nb < NTB; ++nb) {
        bn0[nb] = *(const short8*)(wr[nb] + (it + 1) * 64);
        bn1[nb] = *(const short8*)(wr[nb] + (it + 1) * 64 + 32);
      }
    }
    short8 a0 = *(const short8*)(xrow + it * 64);
    short8 a1 = *(const short8*)(xrow + it * 64 + 32);
    #pragma unroll
    for (int nb = 0; nb < NTB; ++nb) {
      acc[nb] = __builtin_amdgcn_mfma_f32_16x16x32_bf16(a0, bc0[nb], acc[nb], 0, 0, 0);
      acc[nb] = __builtin_amdgcn_mfma_f32_16x16x32_bf16(a1, bc1[nb], acc[nb], 0, 0, 0);
    }
    if (it + 1 < NIT) {
      #pragma unroll
      for (int nb = 0; nb < NTB; ++nb) { bc0[nb] = bn0[nb]; bc1[nb] = bn1[nb]; }
    }
  }

  if (SPLIT_K > 1) {
    #pragma unroll
    for (int nb = 0; nb < NTB; ++nb) {
      int kc = (nsub * NTB + nb) * 16 + lrow;
      #pragma unroll
      for (int r = 0; r < 4; ++r)
        atomicAdd(&dnpart[(kg * 4 + r) * DS + kc], acc[nb][r]);
    }
    __syncthreads();
    for (int i = tid; i < TTOK * KP; i += 256) {
      int tt = i / KP, k = i - tt * KP;
      float v = (k < DS) ? fmaxf(dnpart[tt * DS + k] + bd[k], 0.f) : 0.f;
      dn[tt][k] = f2bf(v);
    }
  } else {
    #pragma unroll
    for (int nb = 0; nb < NTB; ++nb) {
      int kc = (nsub * NTB + nb) * 16 + lrow;
      float bv = bd[kc];
      #pragma unroll
      for (int r = 0; r < 4; ++r)
        dn[kg * 4 + r][kc] = f2bf(fmaxf(acc[nb][r] + bv, 0.f));
    }
  }
  __syncthreads();

  // ---- phase B: up = dn @ Wu + bu -> LDS out tile; B-frags rotated 1 ahead
  short8 afr[KB];
  #pragma unroll
  for (int k = 0; k < KB; ++k) afr[k] = *(const short8*)&dn[lrow][k * 32 + kg * 8];
  const unsigned short* wurow = wu + (size_t)(wv * 12 * 16 + lrow) * KP + kg * 8;

  short8 ub[KB];
  #pragma unroll
  for (int k = 0; k < KB; ++k) ub[k] = *(const short8*)(wurow + k * 32);

  #pragma unroll 2
  for (int nn = 0; nn < 12; ++nn) {
    short8 un[KB];
    if (nn + 1 < 12) {
      #pragma unroll
      for (int k = 0; k < KB; ++k)
        un[k] = *(const short8*)(wurow + (size_t)(nn + 1) * 16 * KP + k * 32);
    }
    f32x4 c = {0.f, 0.f, 0.f, 0.f};
    #pragma unroll
    for (int k = 0; k < KB; ++k)
      c = __builtin_amdgcn_mfma_f32_16x16x32_bf16(afr[k], ub[k], c, 0, 0, 0);
    int dcol = (wv * 12 + nn) * 16 + lrow;
    float bv = bu[dcol];
    #pragma unroll
    for (int r = 0; r < 4; ++r)
      OL(kg * 4 + r)[dcol] = f2bf(c[r] + bv);
    if (nn + 1 < 12) {
      #pragma unroll
      for (int k = 0; k < KB; ++k) ub[k] = un[k];
    }
  }
  __syncthreads();

  // ---- stage-out: wave wv bursts its 4 rows: out = ol + x (residual, L2/L3)
  #pragma unroll
  for (int i = 0; i < 4; ++i) {
    int r = wv * 4 + i;
    int t = mytk[i];
    if (t < 0) continue;
    const float* xsrc = x + (size_t)t * DIM;
    float* dst = out + (size_t)t * DIM;
    #pragma unroll
    for (int j = 0; j < 3; ++j) {
      int c = j * 256 + lane * 4;
      float4 xv = *(const float4*)(xsrc + c);
      ushort4 ub4 = *(const ushort4*)(OL(r) + c);
      float4 o;
      o.x = xv.x + bf2f(ub4.x);
      o.y = xv.y + bf2f(ub4.y);
      o.z = xv.z + bf2f(ub4.z);
      o.w = xv.w + bf2f(ub4.w);
      *(float4*)(dst + c) = o;
    }
  }
  __syncthreads();   // OL reads done before next tile's convert rewrites xs
  #undef XS
  #undef OL
}

__global__ __launch_bounds__(256, 4) void moe_main(
    const float* __restrict__ x,
    const int* __restrict__ meta, const int* __restrict__ lists,
    const unsigned short* __restrict__ wdT, const unsigned short* __restrict__ wuT,
    const float* __restrict__ bd0, const float* __restrict__ bd1,
    const float* __restrict__ bd2, const float* __restrict__ bd3,
    const float* __restrict__ bu0, const float* __restrict__ bu1,
    const float* __restrict__ bu2, const float* __restrict__ bu3,
    float* __restrict__ out) {
  __shared__ unsigned short xsol[TTOK * 776];  // x tile / out tile (overlaid)
  __shared__ float dnpart[TTOK * 32];
  __shared__ unsigned short dn[TTOK][136];
  int tid = threadIdx.x, wv = tid >> 6, lane = tid & 63;
  const int* ts = meta + 8;
  int ntiles = ts[4];
  int w0 = blockIdx.x;
  if (w0 >= ntiles) return;

  Pref p;
  issue_prefetch(w0, wv, lane, meta, lists, x, p);

  for (int w = w0; w < ntiles; w += GRID_MAIN) {
    // ---- convert staged tile into LDS; issue sync loads for rows 2-3 first
    int t2 = p.tk[2], t3 = p.tk[3];
    float4 s[6];
    {
      const float* s2 = x + (size_t)((t2 >= 0) ? t2 : 0) * DIM;
      const float* s3 = x + (size_t)((t3 >= 0) ? t3 : 0) * DIM;
      #pragma unroll
      for (int j = 0; j < 3; ++j) {
        float4 a = {0.f, 0.f, 0.f, 0.f}, b = {0.f, 0.f, 0.f, 0.f};
        if (t2 >= 0) a = *(const float4*)(s2 + j * 256 + lane * 4);
        if (t3 >= 0) b = *(const float4*)(s3 + j * 256 + lane * 4);
        s[j] = a; s[3 + j] = b;
      }
    }
    // prefetched rows 0-1 -> LDS
    #pragma unroll
    for (int i = 0; i < 2; ++i) {
      int r = wv * 4 + i;
      #pragma unroll
      for (int j = 0; j < 3; ++j) {
        float4 vv = p.v[i * 3 + j];
        ushort4 b;
        b.x = f2bf(vv.x); b.y = f2bf(vv.y); b.z = f2bf(vv.z); b.w = f2bf(vv.w);
        *(ushort4*)(xsol + r * 776 + j * 256 + lane * 4) = b;
      }
    }
    // sync rows 2-3 -> LDS
    #pragma unroll
    for (int i = 0; i < 2; ++i) {
      int r = wv * 4 + 2 + i;
      #pragma unroll
      for (int j = 0; j < 3; ++j) {
        float4 vv = s[i * 3 + j];
        ushort4 b;
        b.x = f2bf(vv.x); b.y = f2bf(vv.y); b.z = f2bf(vv.z); b.w = f2bf(vv.w);
        *(ushort4*)(xsol + r * 776 + j * 256 + lane * 4) = b;
      }
    }
    int mytk[4];
    #pragma unroll
    for (int i = 0; i < 4; ++i) mytk[i] = p.tk[i];

    // ---- issue next tile's prefetch (stays in flight across compute)
    int wn = w + GRID_MAIN;
    if (wn < ntiles) issue_prefetch(wn, wv, lane, meta, lists, x, p);

    // ---- expert dispatch
    int e = (w >= ts[2]) ? ((w >= ts[3]) ? 3 : 2) : ((w >= ts[1]) ? 1 : 0);
    if (e == 0)
      moe_tile<0>(wv, lane, tid, x, wdT, wuT, bd0, bu0, out, mytk, xsol, dnpart, dn);
    else if (e == 1)
      moe_tile<1>(wv, lane, tid, x, wdT, wuT, bd1, bu1, out, mytk, xsol, dnpart, dn);
    else if (e == 2)
      moe_tile<2>(wv, lane, tid, x, wdT, wuT, bd2, bu2, out, mytk, xsol, dnpart, dn);
    else
      moe_tile<3>(wv, lane, tid, x, wdT, wuT, bd3, bu3, out, mytk, xsol, dnpart, dn);
  }
}

extern "C" void kernel_launch(void* const* d_in, const int* in_sizes, int n_in,
                              void* d_out, int out_size, void* d_ws, size_t ws_size,
                              hipStream_t stream) {
  const float* x = (const float*)d_in[0];
  const int* mask = (const int*)d_in[1];
  const float* Wd[4]; const float* bd[4]; const float* Wu[4]; const float* bu[4];
  for (int i = 0; i < 4; ++i) {
    Wd[i] = (const float*)d_in[2 + 4 * i];
    bd[i] = (const float*)d_in[3 + 4 * i];
    Wu[i] = (const float*)d_in[4 + 4 * i];
    bu[i] = (const float*)d_in[5 + 4 * i];
  }
  char* ws = (char*)d_ws;
  int* hist = (int*)ws;                                  // 2048 B
  int* base = (int*)(ws + 2048);                         // 2048 B
  int* meta = (int*)(ws + 4096);                         // 64 B
  int* lists = (int*)(ws + 4352);                        // 131072 B (sorted, concatenated)
  unsigned short* wdT = (unsigned short*)(ws + 135424);  // 368640 B
  unsigned short* wuT = (unsigned short*)(ws + 504064);  // 393216 B

  hist_kernel<<<NBLK, 256, 0, stream>>>(mask, hist);
  scan_kernel<<<1, 64, 0, stream>>>(hist, base, meta);
  scatter_kernel<<<NBLK, 256, 0, stream>>>(mask, base, lists);
  prep_kernel<<<dim3(4, 32), 256, 0, stream>>>(Wd[0], Wd[1], Wd[2], Wd[3],
                                               Wu[0], Wu[1], Wu[2], Wu[3], wdT, wuT);
  moe_main<<<GRID_MAIN, 256, 0, stream>>>(x, meta, lists, wdT, wuT,
                                          bd[0], bd[1], bd[2], bd[3],
                                          bu[0], bu[1], bu[2], bu[3],
                                          (float*)d_out);
}

// Round 18
// 96.293 us; speedup vs baseline: 1.0493x; 1.0493x over previous
//
#include <hip/hip_runtime.h>
#include <hip/hip_bf16.h>

#define DIM 768
#define NTOK 32768
#define TTOK 16
#define NBLK 128
#define GRID_MAIN 1024

typedef __attribute__((ext_vector_type(8))) short short8;
typedef __attribute__((ext_vector_type(4))) float f32x4;

__device__ __forceinline__ unsigned short f2bf(float f) {
  union { float f; unsigned int u; } v; v.f = f;
  unsigned int u = v.u;
  return (unsigned short)((u + 0x7fffu + ((u >> 16) & 1u)) >> 16);
}
__device__ __forceinline__ float bf2f(unsigned short u) {
  union { unsigned int u; float f; } v; v.u = ((unsigned int)u) << 16; return v.f;
}

// ---- pass 1: per-(block,expert) histogram
__global__ void hist_kernel(const int* __restrict__ mask, int* __restrict__ hist) {
  int tid = threadIdx.x, b = blockIdx.x;
  int gid = b * 256 + tid;
  int wv = tid >> 6, lane = tid & 63;
  int e = mask[gid] & 3;
  __shared__ int wcnt[4][4];
  #pragma unroll
  for (int q = 0; q < 4; ++q) {
    unsigned long long m = __ballot(e == q);
    if (lane == 0) wcnt[wv][q] = __popcll(m);
  }
  __syncthreads();
  if (tid < 4)
    hist[tid * NBLK + b] = wcnt[0][tid] + wcnt[1][tid] + wcnt[2][tid] + wcnt[3][tid];
}

// ---- pass 2: single-wave exclusive scan over 512 (expert-major) entries
__global__ void scan_kernel(const int* __restrict__ hist, int* __restrict__ base,
                            int* __restrict__ meta) {
  int lane = threadIdx.x;  // 64 threads
  int v[8];
  int lsum = 0;
  #pragma unroll
  for (int j = 0; j < 8; ++j) {
    int t = hist[lane * 8 + j];
    v[j] = lsum; lsum += t;
  }
  int inc = lsum;
  #pragma unroll
  for (int d = 1; d < 64; d <<= 1) {
    int u = __shfl_up(inc, d);
    if (lane >= d) inc += u;
  }
  int excl = inc - lsum;
  #pragma unroll
  for (int j = 0; j < 8; ++j) base[lane * 8 + j] = excl + v[j];
  __syncthreads();
  if (lane == 0) {
    int est[5];
    #pragma unroll
    for (int e = 0; e < 4; ++e) est[e] = base[e * NBLK];
    est[4] = NTOK;
    int s = 0;
    #pragma unroll
    for (int e = 0; e < 5; ++e) meta[e] = est[e];
    #pragma unroll
    for (int e = 0; e < 4; ++e) {
      meta[8 + e] = s;
      s += (est[e + 1] - est[e] + TTOK - 1) / TTOK;
    }
    meta[12] = s;
  }
}

// ---- pass 3: scatter tokens to exact sorted positions
__global__ void scatter_kernel(const int* __restrict__ mask, const int* __restrict__ base,
                               int* __restrict__ lists) {
  int tid = threadIdx.x, b = blockIdx.x;
  int gid = b * 256 + tid;
  int wv = tid >> 6, lane = tid & 63;
  int e = mask[gid] & 3;
  __shared__ int wcnt[4][4];
  __shared__ int wbase[4][4];
  unsigned long long lt = (1ull << lane) - 1ull;
  int rank = 0;
  #pragma unroll
  for (int q = 0; q < 4; ++q) {
    unsigned long long m = __ballot(e == q);
    if (e == q) rank = __popcll(m & lt);
    if (lane == 0) wcnt[wv][q] = __popcll(m);
  }
  __syncthreads();
  if (tid < 4) {
    int s = 0;
    #pragma unroll
    for (int w2 = 0; w2 < 4; ++w2) { int c = wcnt[w2][tid]; wbase[w2][tid] = s; s += c; }
  }
  __syncthreads();
  lists[base[e * NBLK + b] + wbase[wv][e] + rank] = gid;
}

// ---- weight repack to bf16 (WdT [ds][768], WuT [768][KP] zero-padded)
__global__ void prep_kernel(const float* __restrict__ Wd0, const float* __restrict__ Wd1,
                            const float* __restrict__ Wd2, const float* __restrict__ Wd3,
                            const float* __restrict__ Wu0, const float* __restrict__ Wu1,
                            const float* __restrict__ Wu2, const float* __restrict__ Wu3,
                            unsigned short* __restrict__ wdT, unsigned short* __restrict__ wuT) {
  int e = blockIdx.x;
  int ds = 16 << e;
  int lgK = (e == 0) ? 5 : (4 + e);
  int KP = 1 << lgK;
  const float* Wd = (e == 0) ? Wd0 : (e == 1) ? Wd1 : (e == 2) ? Wd2 : Wd3;
  const float* Wu = (e == 0) ? Wu0 : (e == 1) ? Wu1 : (e == 2) ? Wu2 : Wu3;
  const int WOFF[4] = {0, 12288, 36864, 86016};
  const int UOFF[4] = {0, 24576, 49152, 98304};
  int stride = gridDim.y * 256;
  int start = blockIdx.y * 256 + threadIdx.x;
  int nd = ds * DIM;
  for (int i = start; i < nd; i += stride) {
    int k = i / DIM, d = i - k * DIM;
    wdT[WOFF[e] + i] = f2bf(Wd[d * ds + k]);
  }
  int nu = DIM << lgK;
  for (int i = start; i < nu; i += stride) {
    int dc = i >> lgK, k = i & (KP - 1);
    wuT[UOFF[e] + i] = (k < ds) ? f2bf(Wu[k * DIM + dc]) : (unsigned short)0;
  }
}

// Prefetched state for the NEXT tile: all 4 token ids of this wave's quad,
// plus the x-data of rows 0-1 (rows 2-3 are loaded at convert time).
struct Pref {
  float4 v[6];
  int tk[4];
};

__device__ __forceinline__ void issue_prefetch(
    int w, int wv, int lane,
    const int* __restrict__ meta, const int* __restrict__ lists,
    const float* __restrict__ x, Pref& p) {
  const int* ts = meta + 8;
  int e = (w >= ts[2]) ? ((w >= ts[3]) ? 3 : 2) : ((w >= ts[1]) ? 1 : 0);
  int base = (w - ts[e]) * TTOK;
  int cnt = meta[e + 1] - meta[e];
  const int* listsE = lists + meta[e];
  #pragma unroll
  for (int i = 0; i < 4; ++i) {
    int r = base + wv * 4 + i;
    p.tk[i] = (r < cnt) ? listsE[r] : -1;
  }
  #pragma unroll
  for (int i = 0; i < 2; ++i) {
    int t = p.tk[i];
    const float* src = x + (size_t)((t >= 0) ? t : 0) * DIM;
    #pragma unroll
    for (int j = 0; j < 3; ++j) {
      float4 vv = {0.f, 0.f, 0.f, 0.f};
      if (t >= 0) vv = *(const float4*)(src + j * 256 + lane * 4);
      p.v[i * 3 + j] = vv;
    }
  }
}

// ---- per-tile compute: phases A/B + burst stage-out
template <int E>
__device__ __forceinline__ void moe_tile(
    int wv, int lane, int tid,
    const float* __restrict__ x,
    const unsigned short* __restrict__ wdT, const unsigned short* __restrict__ wuT,
    const float* __restrict__ bd, const float* __restrict__ bu,
    float* __restrict__ out, const int mytk[4],
    unsigned short* xsol, float* dnpart, unsigned short (*dn)[136]) {
  constexpr int DS = 16 << E;
  constexpr int KP = (E == 0) ? 32 : DS;
  constexpr int NTA = DS / 16;
  constexpr int SPLIT_N = (NTA < 4) ? NTA : 4;   // 1,2,4,4
  constexpr int SPLIT_K = 4 / SPLIT_N;           // 4,2,1,1
  constexpr int NTB = NTA / SPLIT_N;             // 1,1,1,2
  constexpr int KLEN = DIM / SPLIT_K;            // 192,384,768,768
  constexpr int KB = KP / 32;                    // 1,1,2,4
  constexpr int WOFF[4] = {0, 12288, 36864, 86016};
  constexpr int UOFF[4] = {0, 24576, 49152, 98304};
  const unsigned short* wd = wdT + WOFF[E];
  const unsigned short* wu = wuT + UOFF[E];
  #define XS(r) (xsol + (r) * 776)
  #define OL(r) (xsol + (r) * 772)

  int lrow = lane & 15, kg = lane >> 4;

  if (SPLIT_K > 1) {
    for (int i = tid; i < TTOK * DS; i += 256) dnpart[i] = 0.f;
  }
  __syncthreads();   // xs staged by all waves + dnpart zeroed

  // ---- phase A: dn = relu(X @ Wd + bd), A-frags from LDS
  int nsub = wv % SPLIT_N, ksub = wv / SPLIT_N;
  int d_base = ksub * KLEN;

  f32x4 acc[NTB];
  #pragma unroll
  for (int nb = 0; nb < NTB; ++nb) acc[nb] = f32x4{0.f, 0.f, 0.f, 0.f};

  for (int d0 = 0; d0 < KLEN; d0 += 64) {
    #pragma unroll
    for (int u = 0; u < 2; ++u) {
      int d = d_base + d0 + u * 32;
      short8 a = *(const short8*)(XS(lrow) + d + kg * 8);
      #pragma unroll
      for (int nb = 0; nb < NTB; ++nb) {
        int n = nsub * NTB + nb;
        short8 b = *(const short8*)(wd + (size_t)(n * 16 + lrow) * DIM + d + kg * 8);
        acc[nb] = __builtin_amdgcn_mfma_f32_16x16x32_bf16(a, b, acc[nb], 0, 0, 0);
      }
    }
  }

  if (SPLIT_K > 1) {
    #pragma unroll
    for (int nb = 0; nb < NTB; ++nb) {
      int kc = (nsub * NTB + nb) * 16 + lrow;
      #pragma unroll
      for (int r = 0; r < 4; ++r)
        atomicAdd(&dnpart[(kg * 4 + r) * DS + kc], acc[nb][r]);
    }
    __syncthreads();
    for (int i = tid; i < TTOK * KP; i += 256) {
      int tt = i / KP, k = i - tt * KP;
      float v = (k < DS) ? fmaxf(dnpart[tt * DS + k] + bd[k], 0.f) : 0.f;
      dn[tt][k] = f2bf(v);
    }
  } else {
    #pragma unroll
    for (int nb = 0; nb < NTB; ++nb) {
      int kc = (nsub * NTB + nb) * 16 + lrow;
      float bv = bd[kc];
      #pragma unroll
      for (int r = 0; r < 4; ++r)
        dn[kg * 4 + r][kc] = f2bf(fmaxf(acc[nb][r] + bv, 0.f));
    }
  }
  __syncthreads();

  // ---- phase B: up_partial = dn @ Wu + bu -> LDS out tile (bf16, overlays xs)
  short8 afr[KB];
  #pragma unroll
  for (int k = 0; k < KB; ++k) afr[k] = *(const short8*)&dn[lrow][k * 32 + kg * 8];

  #pragma unroll 3
  for (int nn = 0; nn < 12; ++nn) {
    int n = wv * 12 + nn;
    f32x4 c = {0.f, 0.f, 0.f, 0.f};
    #pragma unroll
    for (int k = 0; k < KB; ++k) {
      short8 b = *(const short8*)(wu + (size_t)(n * 16 + lrow) * KP + k * 32 + kg * 8);
      c = __builtin_amdgcn_mfma_f32_16x16x32_bf16(afr[k], b, c, 0, 0, 0);
    }
    int dcol = n * 16 + lrow;
    float bv = bu[dcol];
    #pragma unroll
    for (int r = 0; r < 4; ++r)
      OL(kg * 4 + r)[dcol] = f2bf(c[r] + bv);
  }
  __syncthreads();

  // ---- stage-out: wave wv bursts its 4 rows: out = ol + x (residual, L2/L3)
  #pragma unroll
  for (int i = 0; i < 4; ++i) {
    int r = wv * 4 + i;
    int t = mytk[i];
    if (t < 0) continue;
    const float* xsrc = x + (size_t)t * DIM;
    float* dst = out + (size_t)t * DIM;
    #pragma unroll
    for (int j = 0; j < 3; ++j) {
      int c = j * 256 + lane * 4;
      float4 xv = *(const float4*)(xsrc + c);
      ushort4 ub = *(const ushort4*)(OL(r) + c);
      float4 o;
      o.x = xv.x + bf2f(ub.x);
      o.y = xv.y + bf2f(ub.y);
      o.z = xv.z + bf2f(ub.z);
      o.w = xv.w + bf2f(ub.w);
      *(float4*)(dst + c) = o;
    }
  }
  __syncthreads();   // OL reads done before next tile's convert rewrites xs
  #undef XS
  #undef OL
}

__global__ __launch_bounds__(256, 4) void moe_main(
    const float* __restrict__ x,
    const int* __restrict__ meta, const int* __restrict__ lists,
    const unsigned short* __restrict__ wdT, const unsigned short* __restrict__ wuT,
    const float* __restrict__ bd0, const float* __restrict__ bd1,
    const float* __restrict__ bd2, const float* __restrict__ bd3,
    const float* __restrict__ bu0, const float* __restrict__ bu1,
    const float* __restrict__ bu2, const float* __restrict__ bu3,
    float* __restrict__ out) {
  __shared__ unsigned short xsol[TTOK * 776];  // x tile / out tile (overlaid)
  __shared__ float dnpart[TTOK * 32];
  __shared__ unsigned short dn[TTOK][136];
  int tid = threadIdx.x, wv = tid >> 6, lane = tid & 63;
  const int* ts = meta + 8;
  int ntiles = ts[4];
  int w0 = blockIdx.x;
  if (w0 >= ntiles) return;

  Pref p;
  issue_prefetch(w0, wv, lane, meta, lists, x, p);

  for (int w = w0; w < ntiles; w += GRID_MAIN) {
    // ---- convert staged tile into LDS; issue sync loads for rows 2-3 first
    int t2 = p.tk[2], t3 = p.tk[3];
    float4 s[6];
    {
      const float* s2 = x + (size_t)((t2 >= 0) ? t2 : 0) * DIM;
      const float* s3 = x + (size_t)((t3 >= 0) ? t3 : 0) * DIM;
      #pragma unroll
      for (int j = 0; j < 3; ++j) {
        float4 a = {0.f, 0.f, 0.f, 0.f}, b = {0.f, 0.f, 0.f, 0.f};
        if (t2 >= 0) a = *(const float4*)(s2 + j * 256 + lane * 4);
        if (t3 >= 0) b = *(const float4*)(s3 + j * 256 + lane * 4);
        s[j] = a; s[3 + j] = b;
      }
    }
    // prefetched rows 0-1 -> LDS
    #pragma unroll
    for (int i = 0; i < 2; ++i) {
      int r = wv * 4 + i;
      #pragma unroll
      for (int j = 0; j < 3; ++j) {
        float4 vv = p.v[i * 3 + j];
        ushort4 b;
        b.x = f2bf(vv.x); b.y = f2bf(vv.y); b.z = f2bf(vv.z); b.w = f2bf(vv.w);
        *(ushort4*)(xsol + r * 776 + j * 256 + lane * 4) = b;
      }
    }
    // sync rows 2-3 -> LDS
    #pragma unroll
    for (int i = 0; i < 2; ++i) {
      int r = wv * 4 + 2 + i;
      #pragma unroll
      for (int j = 0; j < 3; ++j) {
        float4 vv = s[i * 3 + j];
        ushort4 b;
        b.x = f2bf(vv.x); b.y = f2bf(vv.y); b.z = f2bf(vv.z); b.w = f2bf(vv.w);
        *(ushort4*)(xsol + r * 776 + j * 256 + lane * 4) = b;
      }
    }
    int mytk[4];
    #pragma unroll
    for (int i = 0; i < 4; ++i) mytk[i] = p.tk[i];

    // ---- issue next tile's prefetch (stays in flight across compute)
    int wn = w + GRID_MAIN;
    if (wn < ntiles) issue_prefetch(wn, wv, lane, meta, lists, x, p);

    // ---- expert dispatch
    int e = (w >= ts[2]) ? ((w >= ts[3]) ? 3 : 2) : ((w >= ts[1]) ? 1 : 0);
    if (e == 0)
      moe_tile<0>(wv, lane, tid, x, wdT, wuT, bd0, bu0, out, mytk, xsol, dnpart, dn);
    else if (e == 1)
      moe_tile<1>(wv, lane, tid, x, wdT, wuT, bd1, bu1, out, mytk, xsol, dnpart, dn);
    else if (e == 2)
      moe_tile<2>(wv, lane, tid, x, wdT, wuT, bd2, bu2, out, mytk, xsol, dnpart, dn);
    else
      moe_tile<3>(wv, lane, tid, x, wdT, wuT, bd3, bu3, out, mytk, xsol, dnpart, dn);
  }
}

extern "C" void kernel_launch(void* const* d_in, const int* in_sizes, int n_in,
                              void* d_out, int out_size, void* d_ws, size_t ws_size,
                              hipStream_t stream) {
  const float* x = (const float*)d_in[0];
  const int* mask = (const int*)d_in[1];
  const float* Wd[4]; const float* bd[4]; const float* Wu[4]; const float* bu[4];
  for (int i = 0; i < 4; ++i) {
    Wd[i] = (const float*)d_in[2 + 4 * i];
    bd[i] = (const float*)d_in[3 + 4 * i];
    Wu[i] = (const float*)d_in[4 + 4 * i];
    bu[i] = (const float*)d_in[5 + 4 * i];
  }
  char* ws = (char*)d_ws;
  int* hist = (int*)ws;                                  // 2048 B
  int* base = (int*)(ws + 2048);                         // 2048 B
  int* meta = (int*)(ws + 4096);                         // 64 B
  int* lists = (int*)(ws + 4352);                        // 131072 B (sorted, concatenated)
  unsigned short* wdT = (unsigned short*)(ws + 135424);  // 368640 B
  unsigned short* wuT = (unsigned short*)(ws + 504064);  // 393216 B

  hist_kernel<<<NBLK, 256, 0, stream>>>(mask, hist);
  scan_kernel<<<1, 64, 0, stream>>>(hist, base, meta);
  scatter_kernel<<<NBLK, 256, 0, stream>>>(mask, base, lists);
  prep_kernel<<<dim3(4, 32), 256, 0, stream>>>(Wd[0], Wd[1], Wd[2], Wd[3],
                                               Wu[0], Wu[1], Wu[2], Wu[3], wdT, wuT);
  moe_main<<<GRID_MAIN, 256, 0, stream>>>(x, meta, lists, wdT, wuT,
                                          bd[0], bd[1], bd[2], bd[3],
                                          bu[0], bu[1], bu[2], bu[3],
                                          (float*)d_out);
}